// Round 10
// baseline (249.844 us; speedup 1.0000x reference)
//
#include <hip/hip_runtime.h>

// Problem constants
#define S_LEN 256
#define B_SZ  128
#define M_ROWS (S_LEN * B_SZ)          // 32768

typedef __attribute__((ext_vector_type(8))) short bf16x8;
typedef __attribute__((ext_vector_type(4))) float f32x4;

__device__ __forceinline__ unsigned short f2bf(float x) {
    unsigned u = __float_as_uint(x);
    unsigned r = (u + 0x7fffu + ((u >> 16) & 1u)) >> 16;   // RNE
    return (unsigned short)r;
}

__device__ __forceinline__ void gl_lds16(const void* g, void* l) {
    __builtin_amdgcn_global_load_lds(
        (const __attribute__((address_space(1))) unsigned int*)g,
        (__attribute__((address_space(3))) unsigned int*)l,
        16, 0, 0);
}

// ---------------- Pass 1: seq f32 -> bf16 ----------------
__global__ __launch_bounds__(256) void convert_seq(const float* __restrict__ in,
                                                   unsigned short* __restrict__ out,
                                                   long n4) {
    long i = (long)blockIdx.x * blockDim.x + threadIdx.x;
    long stride = (long)gridDim.x * blockDim.x;
    for (; i < n4; i += stride) {
        float4 v = ((const float4*)in)[i];
        ushort4 o;
        o.x = f2bf(v.x); o.y = f2bf(v.y); o.z = f2bf(v.z); o.w = f2bf(v.w);
        ((ushort4*)out)[i] = o;
    }
}

// ---------------- Pass 2: f1,f2 f32 -> bf16 (layer-major) ----------------
__global__ __launch_bounds__(256) void convert_f(const float* __restrict__ f1,
                                                 const float* __restrict__ f2,
                                                 unsigned short* __restrict__ out) {
    int g = blockIdx.x * 256 + threadIdx.x;            // 0..65535 float4 groups
    float4 v = (g < 32768) ? ((const float4*)f1)[g] : ((const float4*)f2)[g - 32768];
    ushort4 o;
    o.x = f2bf(v.x); o.y = f2bf(v.y); o.z = f2bf(v.z); o.w = f2bf(v.w);
    ((ushort4*)out)[g] = o;
}

// ---------------- Pass 3: W [2048][1024] f32 -> Wt [2][1024][2048] bf16 ----------------
__global__ __launch_bounds__(256) void transpose_w(const float* __restrict__ W11,
                                                   const float* __restrict__ W12,
                                                   unsigned short* __restrict__ Wt) {
    const int nt = blockIdx.x, kt = blockIdx.y, layer = blockIdx.z;
    const float* W = layer ? W12 : W11;
    __shared__ float T[64][65];
    const int c = threadIdx.x & 63, r4 = threadIdx.x >> 6;
    const int k0 = kt * 64, n0 = nt * 64;
    #pragma unroll
    for (int p = 0; p < 16; ++p) {
        int r = p * 4 + r4;
        T[r][c] = W[(size_t)(k0 + r) * 1024 + n0 + c];
    }
    __syncthreads();
    unsigned short* Wl = Wt + (size_t)layer * 1024 * 2048;
    #pragma unroll
    for (int p = 0; p < 16; ++p) {
        int n = p * 4 + r4;
        Wl[(size_t)(n0 + n) * 2048 + k0 + c] = f2bf(T[c][n]);
    }
}

// ---------------- Pass 4: c[layer][b][h] = f@W[1024:] + bias  (MFMA 128x128 tile) ----------------
__global__ __launch_bounds__(256) void c_precompute(const unsigned short* __restrict__ fbf, // [2][128][1024]
                                                    const unsigned short* __restrict__ Wt,  // [2][1024][2048]
                                                    const float* __restrict__ b11,
                                                    const float* __restrict__ b12,
                                                    float* __restrict__ cbuf) {            // [2][128][1024]
    __shared__ char smem[32768];
    unsigned short* ldsA = (unsigned short*)smem;            // [128][64]
    unsigned short* ldsB = (unsigned short*)(smem + 16384);  // [128][64]
    const int n0 = blockIdx.x * 128;
    const int layer = blockIdx.y;
    const int tid = threadIdx.x;
    const int w = tid >> 6, l = tid & 63;
    const int wm = w >> 1, wn = w & 1;
    const int lr = l & 15, lg = l >> 4;
    const unsigned short* Af = fbf + (size_t)layer * 128 * 1024;
    const unsigned short* Wl = Wt + (size_t)layer * 1024 * 2048;
    const float* bias = layer ? b12 : b11;

    f32x4 acc[4][4];
    #pragma unroll
    for (int i = 0; i < 4; ++i)
        #pragma unroll
        for (int j = 0; j < 4; ++j)
            #pragma unroll
            for (int e = 0; e < 4; ++e) acc[i][j][e] = 0.f;

    for (int kk = 0; kk < 1024; kk += 64) {
        __syncthreads();
        #pragma unroll
        for (int c = 0; c < 4; ++c) {
            int o = w * 4096 + c * 1024;
            int ob = o + l * 16;
            int row = ob >> 7, kb = ob & 127;
            gl_lds16((const char*)Af + ((size_t)row * 1024 + kk) * 2 + kb, (char*)ldsA + o);
            gl_lds16((const char*)Wl + ((size_t)(n0 + row) * 2048 + 1024 + kk) * 2 + kb, (char*)ldsB + o);
        }
        __syncthreads();
        #pragma unroll
        for (int ks = 0; ks < 2; ++ks) {
            bf16x8 av[4], bv[4];
            #pragma unroll
            for (int i = 0; i < 4; ++i) {
                av[i] = *(const bf16x8*)(ldsA + (wm * 64 + i * 16 + lr) * 64 + ks * 32 + lg * 8);
                bv[i] = *(const bf16x8*)(ldsB + (wn * 64 + i * 16 + lr) * 64 + ks * 32 + lg * 8);
            }
            #pragma unroll
            for (int i = 0; i < 4; ++i)
                #pragma unroll
                for (int j = 0; j < 4; ++j)
                    acc[i][j] = __builtin_amdgcn_mfma_f32_16x16x32_bf16(av[i], bv[j], acc[i][j], 0, 0, 0);
        }
    }
    float* cl = cbuf + (size_t)layer * 128 * 1024;
    #pragma unroll
    for (int i = 0; i < 4; ++i)
        #pragma unroll
        for (int j = 0; j < 4; ++j)
            #pragma unroll
            for (int q = 0; q < 4; ++q) {
                int rr = wm * 64 + i * 16 + lg * 4 + q;
                int hc = n0 + wn * 64 + j * 16 + lr;
                cl[(size_t)rr * 1024 + hc] = acc[i][j][q] + bias[hc];
            }
}

// ================= Pass 5: main fused GEMM =================
// 128x256 tile, BK=32, 8 waves (wave-tile 64x64), dbuf LDS 48 KB ->
// TWO BLOCKS PER CU (96 KB LDS, VGPR<=128, 4 waves/SIMD total).
// Rationale: single-block configs idle the whole CU at each barrier (R9:
// ~50% overhead). Two independent 8-wave blocks overlap: one computes while
// the other drains/syncs. Same 16 waves/CU TLP, decoupled sync domains.
// Per K-step: { STAGE(t+1) early | 8 ds_read frags | 16 MFMA | vmcnt(0)+bar }.
// LDS tile rows = 64 B; swizzle involution x ^= ((x>>7)&3)<<4 (R5-verified,
// SQ_LDS_BANK_CONFLICT = 0). gl_lds: linear dest + inverse-swizzled source.
// XCD decode: mt ≡ bid (mod 8), g fast -> per-XCD set = 8 A-tiles (2 MB)
// + 8 B-tiles (4 MB).

__global__ __launch_bounds__(512, 4) void fused_main(const unsigned short* __restrict__ Abf, // [32768][1024] bf16
                                                     const unsigned short* __restrict__ Wt,  // [2][1024][2048] bf16
                                                     const float* __restrict__ cbuf,         // [2][128][1024]
                                                     const float* __restrict__ W21,
                                                     const float* __restrict__ W22,
                                                     float* __restrict__ sbufp) {            // [8][32768]
    __shared__ char smem[49152];   // 2 bufs x (A 8K + B 16K)
    const int bid = blockIdx.x;
    const int xcd = bid & 7;
    const int idx = bid >> 3;          // 0..255
    const int g   = idx & 7;           // layer*4 + nt  (fast within XCD)
    const int mt  = xcd + 8 * (idx >> 3);  // 0..255  M-tile (128 rows = one s, all b)
    const int layer = g >> 2;
    const int nt    = g & 3;
    const int n0 = nt * 256;

    const int tid = threadIdx.x;
    const int w = tid >> 6, l = tid & 63;
    const int wm = w >> 2, wn = w & 3;  // 2 M-halves x 4 N-quarters (wave tile 64x64)
    const int lr = l & 15, lg = l >> 4;

    const char* Ag = (const char*)Abf + (size_t)mt * 128 * 2048;                          // row stride 2048 B
    const char* Bg = (const char*)(Wt + (size_t)layer * 1024 * 2048) + (size_t)n0 * 4096; // row stride 4096 B

    // staging: 24 KB per K-step = 3 gl_lds/thread.
    // A region 8 KB (rows 0..127), B region 16 KB (rows 0..255), rows = 64 B.
    const int dlocA  = tid * 16;                 // 0..8191
    const int gswA   = dlocA ^ (((dlocA >> 7) & 3) << 4);
    const char* srcA = Ag + (size_t)(gswA >> 6) * 2048 + (gswA & 63);
    const int dlocB0 = tid * 16;                 // B local 0..8191  (rows 0..127)
    const int gswB0  = dlocB0 ^ (((dlocB0 >> 7) & 3) << 4);
    const char* srcB0 = Bg + (size_t)(gswB0 >> 6) * 4096 + (gswB0 & 63);
    const int dlocB1 = 8192 + tid * 16;          // B local 8192..16383 (rows 128..255)
    const int gswB1  = dlocB1 ^ (((dlocB1 >> 7) & 3) << 4);
    const char* srcB1 = Bg + (size_t)(gswB1 >> 6) * 4096 + (gswB1 & 63);
    const int dstW = w * 1024;   // wave-uniform LDS base (HW adds lane*16)

    // fragment LDS offsets (swizzled, loop-invariant); local within A/B region
    int offA[4], offB[4];
    #pragma unroll
    for (int i = 0; i < 4; ++i) {
        int oa = (wm * 64 + i * 16 + lr) * 64 + lg * 16;
        offA[i] = oa ^ (((oa >> 7) & 3) << 4);
        int ob = (wn * 64 + i * 16 + lr) * 64 + lg * 16;
        offB[i] = ob ^ (((ob >> 7) & 3) << 4);
    }

    f32x4 acc[4][4];
    #pragma unroll
    for (int i = 0; i < 4; ++i)
        #pragma unroll
        for (int j = 0; j < 4; ++j)
            #pragma unroll
            for (int e = 0; e < 4; ++e) acc[i][j][e] = 0.f;

#define STAGE(t, bi) do {                                               \
        char* d_ = smem + (bi) * 24576;                                 \
        gl_lds16(srcA  + (size_t)(t) * 64, d_ + dstW);                  \
        gl_lds16(srcB0 + (size_t)(t) * 64, d_ + 8192 + dstW);           \
        gl_lds16(srcB1 + (size_t)(t) * 64, d_ + 16384 + dstW);          \
    } while (0)

#define COMPUTE(bi) do {                                                \
        const char* Ab_ = smem + (bi) * 24576;                          \
        const char* Bb_ = Ab_ + 8192;                                   \
        bf16x8 av_[4], bv_[4];                                          \
        _Pragma("unroll")                                               \
        for (int i_ = 0; i_ < 4; ++i_) {                                \
            av_[i_] = *(const bf16x8*)(Ab_ + offA[i_]);                 \
            bv_[i_] = *(const bf16x8*)(Bb_ + offB[i_]);                 \
        }                                                               \
        _Pragma("unroll")                                               \
        for (int i_ = 0; i_ < 4; ++i_)                                  \
            _Pragma("unroll")                                           \
            for (int j_ = 0; j_ < 4; ++j_)                              \
                acc[i_][j_] = __builtin_amdgcn_mfma_f32_16x16x32_bf16(  \
                    av_[i_], bv_[j_], acc[i_][j_], 0, 0, 0);            \
    } while (0)

#define WAITBAR() do {                                                  \
        __builtin_amdgcn_sched_barrier(0);                              \
        asm volatile("s_waitcnt vmcnt(0)" ::: "memory");                \
        __builtin_amdgcn_sched_barrier(0);                              \
        __builtin_amdgcn_s_barrier();                                   \
        __builtin_amdgcn_sched_barrier(0);                              \
    } while (0)

    // prologue
    STAGE(0, 0);
    WAITBAR();

    // main loop: 32 K-steps, unrolled x2 for static buffer indices
    for (int tt = 0; tt < 32; tt += 2) {
        if (tt + 1 < 32) STAGE(tt + 1, 1);
        COMPUTE(0); WAITBAR();
        if (tt + 2 < 32) STAGE(tt + 2, 0);
        COMPUTE(1); WAITBAR();
    }

#undef STAGE
#undef COMPUTE
#undef WAITBAR

    // ---- epilogue: z = acc + c, h = tanh(z), dot with W21/W22, reduce ----
    const float* cl = cbuf + (size_t)layer * 131072;
    const float* W2 = layer ? W22 : W21;
    float w2v[4];
    #pragma unroll
    for (int j = 0; j < 4; ++j) w2v[j] = W2[n0 + wn * 64 + j * 16 + lr];
    float* red = (float*)smem;   // [128][4]  (final loop barrier fences reuse)
    #pragma unroll
    for (int i = 0; i < 4; ++i) {
        #pragma unroll
        for (int q = 0; q < 4; ++q) {
            int wrow = wm * 64 + i * 16 + lg * 4 + q;    // 0..127 = b index (M-tile = one s)
            float p = 0.f;
            #pragma unroll
            for (int j = 0; j < 4; ++j) {
                int col = n0 + wn * 64 + j * 16 + lr;
                float z = acc[i][j][q] + cl[(size_t)wrow * 1024 + col];
                float e = __expf(2.f * z);
                p += (1.f - 2.f / (e + 1.f)) * w2v[j];
            }
            p += __shfl_xor(p, 1);
            p += __shfl_xor(p, 2);
            p += __shfl_xor(p, 4);
            p += __shfl_xor(p, 8);
            if (lr == 0) red[wrow * 4 + wn] = p;
        }
    }
    __syncthreads();
    if (tid < 128) {
        float v = red[tid * 4 + 0] + red[tid * 4 + 1] + red[tid * 4 + 2] + red[tid * 4 + 3];
        sbufp[(size_t)g * M_ROWS + (size_t)mt * 128 + tid] = v;
    }
}

// ---------------- Pass 6: softmax over s -> coef ----------------
__device__ __forceinline__ float block_max(float v, float* lds) {
    #pragma unroll
    for (int m = 32; m; m >>= 1) v = fmaxf(v, __shfl_xor(v, m));
    if ((threadIdx.x & 63) == 0) lds[threadIdx.x >> 6] = v;
    __syncthreads();
    v = fmaxf(fmaxf(lds[0], lds[1]), fmaxf(lds[2], lds[3]));
    __syncthreads();
    return v;
}
__device__ __forceinline__ float block_sum(float v, float* lds) {
    #pragma unroll
    for (int m = 32; m; m >>= 1) v += __shfl_xor(v, m);
    if ((threadIdx.x & 63) == 0) lds[threadIdx.x >> 6] = v;
    __syncthreads();
    v = lds[0] + lds[1] + lds[2] + lds[3];
    __syncthreads();
    return v;
}

__global__ __launch_bounds__(256) void coef_kernel(const float* __restrict__ sbufp,
                                                   float* __restrict__ coef) {
    __shared__ float lds[4];
    const int b = blockIdx.x, s = threadIdx.x;
    float v1 = 0.f, v2 = 0.f;
    #pragma unroll
    for (int nt = 0; nt < 4; ++nt) {
        v1 += sbufp[(size_t)nt * M_ROWS + (size_t)s * 128 + b];
        v2 += sbufp[(size_t)(4 + nt) * M_ROWS + (size_t)s * 128 + b];
    }
    float m1 = block_max(v1, lds);
    float e1 = expf(v1 - m1);
    float S1 = block_sum(e1, lds);
    float m2 = block_max(v2, lds);
    float e2 = expf(v2 - m2);
    float S2 = block_sum(e2, lds);
    coef[(size_t)s * 128 + b] = (e1 / S1 + e2 / S2) * (0.5f / (float)S_LEN);
}

// ---------------- Pass 7: out[b][d] = sum_s coef[s][b] * seq[s][b][d] ----------------
// Atomic-free: each thread owns one output element, loops all 256 s.
__global__ __launch_bounds__(256) void final_kernel(const float* __restrict__ seq,
                                                    const float* __restrict__ coef,
                                                    float* __restrict__ out) {
    const int b = blockIdx.x, dq = blockIdx.y;
    const int d = dq * 256 + threadIdx.x;
    float a = 0.f;
    #pragma unroll 8
    for (int s = 0; s < 256; ++s) {
        a += coef[(size_t)s * 128 + b] * seq[(size_t)(s * 128 + b) * 1024 + d];
    }
    out[(size_t)b * 1024 + d] = a;
}

extern "C" void kernel_launch(void* const* d_in, const int* in_sizes, int n_in,
                              void* d_out, int out_size, void* d_ws, size_t ws_size,
                              hipStream_t stream) {
    const float* feature1 = (const float*)d_in[0];   // [128,1024]
    const float* feature2 = (const float*)d_in[1];   // [128,1024]
    const float* seq      = (const float*)d_in[2];   // [256,128,1024]
    const float* W11      = (const float*)d_in[3];   // [2048,1024]
    const float* b11      = (const float*)d_in[4];
    const float* W12      = (const float*)d_in[5];
    const float* b12      = (const float*)d_in[6];
    const float* W21      = (const float*)d_in[7];   // [1024,1]
    const float* W22      = (const float*)d_in[9];
    float* out = (float*)d_out;

    char* ws = (char*)d_ws;
    unsigned short* Abf   = (unsigned short*)(ws + 0);                  // 67108864 B
    unsigned short* Wt    = (unsigned short*)(ws + 67108864);           //  8388608 B
    unsigned short* fbf   = (unsigned short*)(ws + 75497472);           //   524288 B
    float*          cbuf  = (float*)(ws + 76021760);                    //  1048576 B
    float*          sbufp = (float*)(ws + 77070336);                    //  1048576 B  [8][32768]
    float*          coef  = (float*)(ws + 78118912);                    //   131072 B

    convert_seq<<<2048, 256, 0, stream>>>(seq, Abf, (long)M_ROWS * 1024 / 4);
    convert_f<<<256, 256, 0, stream>>>(feature1, feature2, fbf);
    transpose_w<<<dim3(16, 32, 2), 256, 0, stream>>>(W11, W12, Wt);
    c_precompute<<<dim3(8, 2), 256, 0, stream>>>(fbf, Wt, b11, b12, cbuf);
    fused_main<<<2048, 512, 0, stream>>>(Abf, Wt, cbuf, W21, W22, sbufp);
    coef_kernel<<<128, 256, 0, stream>>>(sbufp, coef);
    final_kernel<<<dim3(128, 4), 256, 0, stream>>>(seq, coef, out);
}